// Round 1
// baseline (722.152 us; speedup 1.0000x reference)
//
#include <hip/hip_runtime.h>
#include <hip/hip_bf16.h>
#include <stdint.h>

// Problem constants (fixed by the reference).
constexpr int BATCH = 64;
constexpr int T     = 2048;
constexpr int CCH   = 32;
constexpr int OUT_T = 2048;
constexpr int K     = T * CCH;   // 65536
constexpr int N     = OUT_T;     // 2048

// GEMM tiling.
constexpr int TN     = 64;       // n-tile per block
constexpr int KSPLIT = 64;       // K-splits (blocks along K)
constexpr int CK     = K / KSPLIT; // 1024 k per block
constexpr int BK     = 32;       // K-step (MFMA K)

typedef __attribute__((ext_vector_type(8))) short short8;
typedef __attribute__((ext_vector_type(4))) float f32x4;

// Split fp32 -> bf16 hi (truncation) + bf16 lo (RNE of remainder).
// x ~= hi + lo with |err| ~ 2^-17 |x|.
__device__ __forceinline__ void split_bf16(float x, ushort& h, ushort& l) {
  unsigned xb = __float_as_uint(x);
  h = (ushort)(xb >> 16);
  float hf = __uint_as_float(xb & 0xFFFF0000u);
  float lf = x - hf;
  unsigned u = __float_as_uint(lf);
  unsigned r = u + 0x7FFFu + ((u >> 16) & 1u);   // RNE to bf16
  l = (ushort)(r >> 16);
}

__global__ __launch_bounds__(256) void gemm_split_kernel(
    const float* __restrict__ X,      // (64, 65536) row-major
    const float* __restrict__ W,      // (65536, 2048) row-major
    float* __restrict__ def) {        // (64, 2048) fp32, pre-zeroed
  const int bn = blockIdx.x % (N / TN);  // 0..31
  const int bk = blockIdx.x / (N / TN);  // 0..63
  const int tid  = threadIdx.x;
  const int lane = tid & 63;
  const int wave = tid >> 6;             // 4 waves; wave w owns n-frag [16w,16w+16)
  const int r = lane & 15;
  const int g = lane >> 4;

  // LDS tiles: A (64m x 32k) and B^T (64n x 32k), bf16 hi/lo.
  __shared__ ushort Ahi[64][32];
  __shared__ ushort Alo[64][32];
  __shared__ ushort Bhi[64][40];   // stride 40 ushort = 80B (16B aligned rows)
  __shared__ ushort Blo[64][40];

  f32x4 acc[4] = {};               // 4 m-frags (64 rows) x 16 n cols

  const int kbase = bk * CK;

  for (int ks = 0; ks < CK / BK; ++ks) {
    const int k0 = kbase + ks * BK;

    __syncthreads();   // previous iteration's reads done before overwrite

    // ---- stage A: 64 x 32 fp32, thread owns float4 along k ----
#pragma unroll
    for (int it = 0; it < 2; ++it) {
      int flat = it * 256 + tid;         // 0..511
      int m  = flat >> 3;                // 0..63
      int kq = flat & 7;                 // 0..7 (float4 index)
      const float4 v = *(const float4*)&X[(size_t)m * K + k0 + kq * 4];
      ushort h0, h1, h2, h3, l0, l1, l2, l3;
      split_bf16(v.x, h0, l0); split_bf16(v.y, h1, l1);
      split_bf16(v.z, h2, l2); split_bf16(v.w, h3, l3);
      uint2 ph; ph.x = (unsigned)h0 | ((unsigned)h1 << 16);
                ph.y = (unsigned)h2 | ((unsigned)h3 << 16);
      uint2 pl; pl.x = (unsigned)l0 | ((unsigned)l1 << 16);
                pl.y = (unsigned)l2 | ((unsigned)l3 << 16);
      *(uint2*)&Ahi[m][kq * 4] = ph;
      *(uint2*)&Alo[m][kq * 4] = pl;
    }

    // ---- stage B^T: 32k x 64n fp32, thread owns a 4-deep k-column at one n ----
#pragma unroll
    for (int it = 0; it < 2; ++it) {
      int flat = it * 256 + tid;         // 0..511
      int n  = flat & 63;                // 0..63  (wave reads 256B contiguous)
      int kq = flat >> 6;                // 0..7
      float v0 = W[(size_t)(k0 + kq * 4 + 0) * N + bn * TN + n];
      float v1 = W[(size_t)(k0 + kq * 4 + 1) * N + bn * TN + n];
      float v2 = W[(size_t)(k0 + kq * 4 + 2) * N + bn * TN + n];
      float v3 = W[(size_t)(k0 + kq * 4 + 3) * N + bn * TN + n];
      ushort h0, h1, h2, h3, l0, l1, l2, l3;
      split_bf16(v0, h0, l0); split_bf16(v1, h1, l1);
      split_bf16(v2, h2, l2); split_bf16(v3, h3, l3);
      uint2 ph; ph.x = (unsigned)h0 | ((unsigned)h1 << 16);
                ph.y = (unsigned)h2 | ((unsigned)h3 << 16);
      uint2 pl; pl.x = (unsigned)l0 | ((unsigned)l1 << 16);
                pl.y = (unsigned)l2 | ((unsigned)l3 << 16);
      *(uint2*)&Bhi[n][kq * 4] = ph;
      *(uint2*)&Blo[n][kq * 4] = pl;
    }

    __syncthreads();

    // ---- fragments + MFMA: frag k = 8*(lane>>4)+j (contiguous 8) ----
    short8 bh = *(const short8*)&Bhi[wave * 16 + r][g * 8];
    short8 bl = *(const short8*)&Blo[wave * 16 + r][g * 8];
#pragma unroll
    for (int mf = 0; mf < 4; ++mf) {
      short8 ah = *(const short8*)&Ahi[mf * 16 + r][g * 8];
      short8 al = *(const short8*)&Alo[mf * 16 + r][g * 8];
      acc[mf] = __builtin_amdgcn_mfma_f32_16x16x32_bf16(ah, bh, acc[mf], 0, 0, 0);
      acc[mf] = __builtin_amdgcn_mfma_f32_16x16x32_bf16(ah, bl, acc[mf], 0, 0, 0);
      acc[mf] = __builtin_amdgcn_mfma_f32_16x16x32_bf16(al, bh, acc[mf], 0, 0, 0);
    }
  }

  // ---- epilogue: atomically accumulate K-split partials ----
  // C/D layout: col = lane&15 (n), row = 4*(lane>>4) + reg (m within 16-frag).
  const int ncol = bn * TN + wave * 16 + r;
#pragma unroll
  for (int mf = 0; mf < 4; ++mf) {
    const int mbase = mf * 16 + g * 4;
#pragma unroll
    for (int q = 0; q < 4; ++q) {
      atomicAdd(&def[(size_t)(mbase + q) * N + ncol], acc[mf][q]);
    }
  }
}

__global__ __launch_bounds__(256) void resample_kernel(
    const float* __restrict__ X,       // (64, 2048, 32)
    const float* __restrict__ def,     // (64, 2048)
    const float* __restrict__ b_loc,   // (2048,)
    float* __restrict__ out) {         // (64, 2048, 32)
  const int tid = blockIdx.x * 256 + threadIdx.x;  // 64*2048*8 total
  const int c4 = tid & 7;                          // float4 index over C
  const int o  = (tid >> 3) & (OUT_T - 1);
  const int b  = tid >> 14;

  // grid[o] = o exactly (linspace(0, T-1, OUT_T) with T==OUT_T).
  const float x = (float)o + def[b * OUT_T + o] + b_loc[o];
  const float xf = floorf(x);
  const int x0 = (int)xf;
  const int x1 = x0 + 1;
  const int x0c = min(max(x0, 0), T - 1);
  const int x1c = min(max(x1, 0), T - 1);
  const float w0 = (float)x1c - x;    // weights use CLIPPED coords (faithful)
  const float w1 = x - (float)x0c;

  const float4 v0 = *(const float4*)&X[((size_t)b * T + x0c) * CCH + c4 * 4];
  const float4 v1 = *(const float4*)&X[((size_t)b * T + x1c) * CCH + c4 * 4];
  float4 res;
  res.x = w0 * v0.x + w1 * v1.x;
  res.y = w0 * v0.y + w1 * v1.y;
  res.z = w0 * v0.z + w1 * v1.z;
  res.w = w0 * v0.w + w1 * v1.w;
  *(float4*)&out[((size_t)b * OUT_T + o) * CCH + c4 * 4] = res;
}

extern "C" void kernel_launch(void* const* d_in, const int* in_sizes, int n_in,
                              void* d_out, int out_size, void* d_ws, size_t ws_size,
                              hipStream_t stream) {
  const float* X     = (const float*)d_in[0];
  const float* W     = (const float*)d_in[1];
  const float* b_loc = (const float*)d_in[2];
  float* out = (float*)d_out;
  float* def = (float*)d_ws;   // 64*2048 fp32 = 512 KB scratch

  hipMemsetAsync(def, 0, (size_t)BATCH * N * sizeof(float), stream);

  dim3 gblk((N / TN) * KSPLIT);            // 32 * 64 = 2048 blocks
  gemm_split_kernel<<<gblk, 256, 0, stream>>>(X, W, def);

  dim3 rblk((BATCH * OUT_T * 8) / 256);    // 4096 blocks
  resample_kernel<<<rblk, 256, 0, stream>>>(X, def, b_loc, out);
}

// Round 2
// 709.204 us; speedup vs baseline: 1.0183x; 1.0183x over previous
//
#include <hip/hip_runtime.h>
#include <hip/hip_bf16.h>
#include <stdint.h>

// Problem constants (fixed by the reference).
constexpr int BATCH = 64;
constexpr int T     = 2048;
constexpr int CCH   = 32;
constexpr int OUT_T = 2048;
constexpr int K     = T * CCH;   // 65536
constexpr int N     = OUT_T;     // 2048

// GEMM tiling.
constexpr int TN     = 64;         // n-tile per block
constexpr int NBN    = N / TN;     // 32 n-tiles
constexpr int KSPLIT = 64;         // K-splits (blocks along K)
constexpr int CK     = K / KSPLIT; // 1024 k per block
constexpr int BK     = 32;         // K-step (MFMA K)
constexpr int NS     = CK / BK;    // 32 steps
// blocks = NBN * KSPLIT = 2048; XCD swizzle chunk = 2048/8 = 256.

typedef __attribute__((ext_vector_type(8))) short short8;
typedef __attribute__((ext_vector_type(4))) float f32x4;

// Split fp32 -> bf16 hi (truncation) + bf16 lo (RNE of remainder).
// x ~= hi + lo with |err| ~ 2^-16 |x|.  (Numerics identical to round 1.)
__device__ __forceinline__ void split_bf16(float x, ushort& h, ushort& l) {
  unsigned xb = __float_as_uint(x);
  h = (ushort)(xb >> 16);
  float hf = __uint_as_float(xb & 0xFFFF0000u);
  float lf = x - hf;
  unsigned u = __float_as_uint(lf);
  unsigned r = u + 0x7FFFu + ((u >> 16) & 1u);   // RNE to bf16
  l = (ushort)(r >> 16);
}

__global__ __launch_bounds__(256) void gemm_split_kernel(
    const float* __restrict__ X,      // (64, 65536) row-major
    const float* __restrict__ W,      // (65536, 2048) row-major
    float* __restrict__ def) {        // (64, 2048) fp32, pre-zeroed
  // XCD-aware bijective swizzle: HW round-robins blockIdx across 8 XCDs;
  // remap so each XCD owns 256 consecutive logical blocks = 8 bk-groups
  // (8 x 256 KB = 2 MB X working set per XCD -> L2-resident X re-reads).
  const int bid = blockIdx.x;                 // 0..2047
  const int lb  = (bid & 7) * 256 + (bid >> 3);
  const int bn  = lb & (NBN - 1);             // 0..31
  const int bk  = lb >> 5;                    // 0..63

  const int tid  = threadIdx.x;
  const int lane = tid & 63;
  const int wave = tid >> 6;                  // 4 waves; wave w owns n-frag [16w,16w+16)
  const int r = lane & 15;
  const int g = lane >> 4;

  // Double-buffered LDS tiles: A (64m x 32k) and B^T (64n x 32k), bf16 hi/lo.
  __shared__ ushort Ahi[2][64][32];
  __shared__ ushort Alo[2][64][32];
  __shared__ ushort Bhi[2][64][40];   // stride 40 ushort = 80 B (16B-aligned rows)
  __shared__ ushort Blo[2][64][40];

  f32x4 acc[4] = {};                  // 4 m-frags (64 rows) x 16 n cols

  const int kbase = bk * CK;

  // Per-thread staging register state (in-flight global loads).
  float4 aReg[2];
  float  bReg[2][4];

  // ---- issue global loads for step ks (no use yet; latency overlapped) ----
  auto issue_loads = [&](int ks) {
    const int k0 = kbase + ks * BK;
#pragma unroll
    for (int it = 0; it < 2; ++it) {
      int flat = it * 256 + tid;      // 0..511
      int m  = flat >> 3;             // 0..63
      int kq = flat & 7;              // float4 index along k
      aReg[it] = *(const float4*)&X[(size_t)m * K + k0 + kq * 4];
    }
#pragma unroll
    for (int it = 0; it < 2; ++it) {
      int flat = it * 256 + tid;      // 0..511
      int n  = flat & 63;             // wave reads 256B contiguous per k-row
      int kq = flat >> 6;             // 0..7
      const float* wp = &W[(size_t)(k0 + kq * 4) * N + bn * TN + n];
      bReg[it][0] = wp[0];
      bReg[it][1] = wp[N];
      bReg[it][2] = wp[2 * N];
      bReg[it][3] = wp[3 * N];
    }
  };

  // ---- convert in-flight regs -> LDS buffer `buf` ----
  auto stage = [&](int buf) {
#pragma unroll
    for (int it = 0; it < 2; ++it) {
      int flat = it * 256 + tid;
      int m  = flat >> 3;
      int kq = flat & 7;
      const float4 v = aReg[it];
      ushort h0, h1, h2, h3, l0, l1, l2, l3;
      split_bf16(v.x, h0, l0); split_bf16(v.y, h1, l1);
      split_bf16(v.z, h2, l2); split_bf16(v.w, h3, l3);
      uint2 ph; ph.x = (unsigned)h0 | ((unsigned)h1 << 16);
                ph.y = (unsigned)h2 | ((unsigned)h3 << 16);
      uint2 pl; pl.x = (unsigned)l0 | ((unsigned)l1 << 16);
                pl.y = (unsigned)l2 | ((unsigned)l3 << 16);
      *(uint2*)&Ahi[buf][m][kq * 4] = ph;
      *(uint2*)&Alo[buf][m][kq * 4] = pl;
    }
#pragma unroll
    for (int it = 0; it < 2; ++it) {
      int flat = it * 256 + tid;
      int n  = flat & 63;
      int kq = flat >> 6;
      ushort h0, h1, h2, h3, l0, l1, l2, l3;
      split_bf16(bReg[it][0], h0, l0); split_bf16(bReg[it][1], h1, l1);
      split_bf16(bReg[it][2], h2, l2); split_bf16(bReg[it][3], h3, l3);
      uint2 ph; ph.x = (unsigned)h0 | ((unsigned)h1 << 16);
                ph.y = (unsigned)h2 | ((unsigned)h3 << 16);
      uint2 pl; pl.x = (unsigned)l0 | ((unsigned)l1 << 16);
                pl.y = (unsigned)l2 | ((unsigned)l3 << 16);
      *(uint2*)&Bhi[buf][n][kq * 4] = ph;
      *(uint2*)&Blo[buf][n][kq * 4] = pl;
    }
  };

  // ---- prologue: fill buffer 0 ----
  issue_loads(0);
  stage(0);
  __syncthreads();

  // ---- main loop: 1 barrier per K-step, loads for t+1 in flight over MFMA(t) ----
  for (int ks = 0; ks < NS; ++ks) {
    const int cur = ks & 1;
    if (ks + 1 < NS) issue_loads(ks + 1);

    // MFMA from LDS[cur]; frag k = 8*(lane>>4)+j (contiguous 8).
    short8 bh = *(const short8*)&Bhi[cur][wave * 16 + r][g * 8];
    short8 bl = *(const short8*)&Blo[cur][wave * 16 + r][g * 8];
#pragma unroll
    for (int mf = 0; mf < 4; ++mf) {
      short8 ah = *(const short8*)&Ahi[cur][mf * 16 + r][g * 8];
      short8 al = *(const short8*)&Alo[cur][mf * 16 + r][g * 8];
      acc[mf] = __builtin_amdgcn_mfma_f32_16x16x32_bf16(ah, bh, acc[mf], 0, 0, 0);
      acc[mf] = __builtin_amdgcn_mfma_f32_16x16x32_bf16(ah, bl, acc[mf], 0, 0, 0);
      acc[mf] = __builtin_amdgcn_mfma_f32_16x16x32_bf16(al, bh, acc[mf], 0, 0, 0);
    }

    if (ks + 1 < NS) stage(cur ^ 1);   // waits vmcnt on regs, writes other buffer
    __syncthreads();                   // LDS[cur^1] ready; all reads of cur done
  }

  // ---- epilogue: atomically accumulate K-split partials ----
  // C/D layout: col = lane&15 (n), row = 4*(lane>>4) + reg (m within 16-frag).
  const int ncol = bn * TN + wave * 16 + r;
#pragma unroll
  for (int mf = 0; mf < 4; ++mf) {
    const int mbase = mf * 16 + g * 4;
#pragma unroll
    for (int q = 0; q < 4; ++q) {
      atomicAdd(&def[(size_t)(mbase + q) * N + ncol], acc[mf][q]);
    }
  }
}

__global__ __launch_bounds__(256) void resample_kernel(
    const float* __restrict__ X,       // (64, 2048, 32)
    const float* __restrict__ def,     // (64, 2048)
    const float* __restrict__ b_loc,   // (2048,)
    float* __restrict__ out) {         // (64, 2048, 32)
  const int tid = blockIdx.x * 256 + threadIdx.x;  // 64*2048*8 total
  const int c4 = tid & 7;                          // float4 index over C
  const int o  = (tid >> 3) & (OUT_T - 1);
  const int b  = tid >> 14;

  // grid[o] = o exactly (linspace(0, T-1, OUT_T) with T==OUT_T).
  const float x = (float)o + def[b * OUT_T + o] + b_loc[o];
  const float xf = floorf(x);
  const int x0 = (int)xf;
  const int x1 = x0 + 1;
  const int x0c = min(max(x0, 0), T - 1);
  const int x1c = min(max(x1, 0), T - 1);
  const float w0 = (float)x1c - x;    // weights use CLIPPED coords (faithful)
  const float w1 = x - (float)x0c;

  const float4 v0 = *(const float4*)&X[((size_t)b * T + x0c) * CCH + c4 * 4];
  const float4 v1 = *(const float4*)&X[((size_t)b * T + x1c) * CCH + c4 * 4];
  float4 res;
  res.x = w0 * v0.x + w1 * v1.x;
  res.y = w0 * v0.y + w1 * v1.y;
  res.z = w0 * v0.z + w1 * v1.z;
  res.w = w0 * v0.w + w1 * v1.w;
  *(float4*)&out[((size_t)b * OUT_T + o) * CCH + c4 * 4] = res;
}

extern "C" void kernel_launch(void* const* d_in, const int* in_sizes, int n_in,
                              void* d_out, int out_size, void* d_ws, size_t ws_size,
                              hipStream_t stream) {
  const float* X     = (const float*)d_in[0];
  const float* W     = (const float*)d_in[1];
  const float* b_loc = (const float*)d_in[2];
  float* out = (float*)d_out;
  float* def = (float*)d_ws;   // 64*2048 fp32 = 512 KB scratch

  hipMemsetAsync(def, 0, (size_t)BATCH * N * sizeof(float), stream);

  dim3 gblk(NBN * KSPLIT);                 // 2048 blocks
  gemm_split_kernel<<<gblk, 256, 0, stream>>>(X, W, def);

  dim3 rblk((BATCH * OUT_T * 8) / 256);    // 4096 blocks
  resample_kernel<<<rblk, 256, 0, stream>>>(X, def, b_loc, out);
}